// Round 5
// baseline (1274.480 us; speedup 1.0000x reference)
//
#include <hip/hip_runtime.h>
#include <math.h>

#define L_TOTAL 65536
#define D_DIM   256
#define C_ROWS  32
#define N_CHUNK (L_TOTAL / C_ROWS)   // 2048
#define CPB     4                    // chunks per block (one per wave)
#define N_BLK   (N_CHUNK / CPB)      // 512

// Single-pass online-softmax scan with decoupled look-back.
// Wave w of block b owns chunk c = b*4+w (32 rows x 256 dims).
// Lane l owns dims [4l, 4l+4) as float4. No LDS, no __syncthreads.
__global__ __launch_bounds__(256, 2) void aaren_fused(
    const float* __restrict__ K, const float* __restrict__ V,
    const float* __restrict__ q,
    int*   __restrict__ flags,
    float* __restrict__ agg_m, float* __restrict__ agg_u,
    float* __restrict__ agg_w,
    float* __restrict__ inc_m, float* __restrict__ inc_u,
    float* __restrict__ inc_w,
    float* __restrict__ out)
{
    const int t = threadIdx.x;
    const int wave = t >> 6, lane = t & 63;
    const int c = blockIdx.x * CPB + wave;     // chunk id, 0..2047
    const size_t r0 = (size_t)c * C_ROWS;

    const float4 q4 = *reinterpret_cast<const float4*>(q + 4 * lane);

    // ---- phase 1: s[0..31] via float4 dot + 64-lane butterfly --------------
    float s[C_ROWS];
    const float* Kp = K + r0 * D_DIM + 4 * lane;
    #pragma unroll
    for (int b = 0; b < C_ROWS; b += 8) {
        float4 kv[8];
        #pragma unroll
        for (int k = 0; k < 8; ++k)
            kv[k] = *reinterpret_cast<const float4*>(Kp + (size_t)(b + k) * D_DIM);
        #pragma unroll
        for (int k = 0; k < 8; ++k) {
            float d = kv[k].x * q4.x + kv[k].y * q4.y + kv[k].z * q4.z + kv[k].w * q4.w;
            #pragma unroll
            for (int off = 32; off > 0; off >>= 1) d += __shfl_xor(d, off, 64);
            s[b + k] = d;   // all 64 lanes hold the full dot
        }
    }

    float m_c = s[0];
    #pragma unroll
    for (int j = 1; j < C_ROWS; ++j) m_c = fmaxf(m_c, s[j]);

    // ---- chunk aggregate: u_c scalar, w float4 per lane --------------------
    float u_c = 0.f;
    float4 w = make_float4(0.f, 0.f, 0.f, 0.f);
    const float* Vp = V + r0 * D_DIM + 4 * lane;
    #pragma unroll
    for (int b = 0; b < C_ROWS; b += 8) {
        float4 vv[8];
        #pragma unroll
        for (int k = 0; k < 8; ++k)
            vv[k] = *reinterpret_cast<const float4*>(Vp + (size_t)(b + k) * D_DIM);
        #pragma unroll
        for (int k = 0; k < 8; ++k) {
            const float cf = __expf(s[b + k] - m_c);
            u_c += cf;
            w.x = fmaf(cf, vv[k].x, w.x);
            w.y = fmaf(cf, vv[k].y, w.y);
            w.z = fmaf(cf, vv[k].z, w.z);
            w.w = fmaf(cf, vv[k].w, w.w);
        }
    }

    // ---- publish + decoupled look-back ------------------------------------
    float Mp, Up;                 // exclusive prefix (scalar part)
    float4 Wp;                    // exclusive prefix (this lane's dims)

    if (c == 0) {
        Mp = -INFINITY; Up = 0.f; Wp = make_float4(0.f, 0.f, 0.f, 0.f);
        if (lane == 0) { inc_m[0] = m_c; inc_u[0] = u_c; }
        *reinterpret_cast<float4*>(inc_w + 4 * lane) = w;
        __hip_atomic_store(&flags[0], 2, __ATOMIC_RELEASE, __HIP_MEMORY_SCOPE_AGENT);
    } else {
        if (lane == 0) { agg_m[c] = m_c; agg_u[c] = u_c; }
        *reinterpret_cast<float4*>(agg_w + (size_t)c * D_DIM + 4 * lane) = w;
        __hip_atomic_store(&flags[c], 1, __ATOMIC_RELEASE, __HIP_MEMORY_SCOPE_AGENT);

        // suffix accumulator over consumed blocks (empty = identity)
        float M = -INFINITY, U = 0.f;
        float4 W = make_float4(0.f, 0.f, 0.f, 0.f);
        int j = c - 1;
        while (true) {
            int f;
            while ((f = __hip_atomic_load(&flags[j], __ATOMIC_RELAXED,
                                          __HIP_MEMORY_SCOPE_AGENT)) == 0)
                __builtin_amdgcn_s_sleep(1);
            __builtin_amdgcn_fence(__ATOMIC_ACQUIRE, "agent");
            if (f == 2) {
                const float  mj = inc_m[j], uj = inc_u[j];
                const float4 wj = *reinterpret_cast<const float4*>(
                                      inc_w + (size_t)j * D_DIM + 4 * lane);
                const float mn = fmaxf(mj, M);
                const float ea = __expf(mj - mn), eb = __expf(M - mn);
                U   = uj   * ea + U   * eb;
                W.x = wj.x * ea + W.x * eb;
                W.y = wj.y * ea + W.y * eb;
                W.z = wj.z * ea + W.z * eb;
                W.w = wj.w * ea + W.w * eb;
                M = mn;
                break;
            } else {
                const float  mj = agg_m[j], uj = agg_u[j];
                const float4 wj = *reinterpret_cast<const float4*>(
                                      agg_w + (size_t)j * D_DIM + 4 * lane);
                const float mn = fmaxf(mj, M);
                const float ea = __expf(mj - mn), eb = __expf(M - mn);
                U   = uj   * ea + U   * eb;
                W.x = wj.x * ea + W.x * eb;
                W.y = wj.y * ea + W.y * eb;
                W.z = wj.z * ea + W.z * eb;
                W.w = wj.w * ea + W.w * eb;
                M = mn;
                --j;
            }
        }
        Mp = M; Up = U; Wp = W;

        // inclusive(c) = prefix (+) own aggregate; publish ASAP
        const float mi = fmaxf(Mp, m_c);
        const float ea = __expf(Mp - mi), eb = __expf(m_c - mi);
        const float ui = Up * ea + u_c * eb;
        float4 wi;
        wi.x = Wp.x * ea + w.x * eb;
        wi.y = Wp.y * ea + w.y * eb;
        wi.z = Wp.z * ea + w.z * eb;
        wi.w = Wp.w * ea + w.w * eb;
        if (lane == 0) { inc_m[c] = mi; inc_u[c] = ui; }
        *reinterpret_cast<float4*>(inc_w + (size_t)c * D_DIM + 4 * lane) = wi;
        __hip_atomic_store(&flags[c], 2, __ATOMIC_RELEASE, __HIP_MEMORY_SCOPE_AGENT);
    }

    // ---- output: reference recurrence seeded with (Mp, Up, Wp) -------------
    float  m_run = Mp, u_run = Up;
    float4 W = Wp;
    float* Op = out + r0 * D_DIM + 4 * lane;
    #pragma unroll
    for (int b = 0; b < C_ROWS; b += 8) {
        float4 vv[8];
        #pragma unroll
        for (int k = 0; k < 8; ++k)
            vv[k] = *reinterpret_cast<const float4*>(Vp + (size_t)(b + k) * D_DIM);
        #pragma unroll
        for (int k = 0; k < 8; ++k) {
            const float sj = s[b + k];
            const float mn = fmaxf(m_run, sj);
            const float ep = __expf(m_run - mn), ec = __expf(sj - mn);
            u_run = u_run * ep + ec;
            W.x = W.x * ep + vv[k].x * ec;
            W.y = W.y * ep + vv[k].y * ec;
            W.z = W.z * ep + vv[k].z * ec;
            W.w = W.w * ep + vv[k].w * ec;
            m_run = mn;
            const float r = 1.0f / u_run;
            float4 o;
            o.x = W.x * r; o.y = W.y * r; o.z = W.z * r; o.w = W.w * r;
            *reinterpret_cast<float4*>(Op + (size_t)(b + k) * D_DIM) = o;
        }
    }
}

extern "C" void kernel_launch(void* const* d_in, const int* in_sizes, int n_in,
                              void* d_out, int out_size, void* d_ws, size_t ws_size,
                              hipStream_t stream) {
    const float* K = (const float*)d_in[0];
    const float* V = (const float*)d_in[1];
    const float* q = (const float*)d_in[2];
    float* out = (float*)d_out;

    // ws layout (all 16B-aligned)
    int*   flags = (int*)d_ws;                          // 2048 ints = 8 KB
    float* base  = (float*)d_ws + N_CHUNK;              // after flags
    float* agg_m = base;                                // 2048
    float* agg_u = agg_m + N_CHUNK;                     // 2048
    float* inc_m = agg_u + N_CHUNK;                     // 2048
    float* inc_u = inc_m + N_CHUNK;                     // 2048
    float* agg_w = inc_u + N_CHUNK;                     // 2048*256
    float* inc_w = agg_w + (size_t)N_CHUNK * D_DIM;     // 2048*256

    hipMemsetAsync(flags, 0, N_CHUNK * sizeof(int), stream);
    aaren_fused<<<N_BLK, 256, 0, stream>>>(K, V, q, flags,
                                           agg_m, agg_u, agg_w,
                                           inc_m, inc_u, inc_w, out);
}

// Round 6
// 183.077 us; speedup vs baseline: 6.9614x; 6.9614x over previous
//
#include <hip/hip_runtime.h>
#include <math.h>

#define L_TOTAL 65536
#define D_DIM   256
#define C_ROWS  32                    // rows per chunk
#define N_CHUNK (L_TOTAL / C_ROWS)    // 2048
#define SUPER   32                    // chunks per super-chunk
#define N_SUPER (N_CHUNK / SUPER)     // 64

typedef float vf4 __attribute__((ext_vector_type(4)));

// ---------------- kA: per-chunk aggregates (one barrier) -------------------
__global__ __launch_bounds__(256) void kA_aggregate(
    const float* __restrict__ K, const float* __restrict__ V,
    const float* __restrict__ q,
    float* __restrict__ s_g, float* __restrict__ cm,
    float* __restrict__ cu, float* __restrict__ cw)
{
    const int t = threadIdx.x;
    const int c = blockIdx.x;
    const int r0 = c * C_ROWS;
    const int wave = t >> 6, lane = t & 63;

    __shared__ float s_lds[C_ROWS];

    // V loads first (V should stay LLC-resident for kF)
    float v[C_ROWS];
    const float* Vp = V + (size_t)r0 * D_DIM + t;
    #pragma unroll
    for (int j = 0; j < C_ROWS; ++j) v[j] = Vp[(size_t)j * D_DIM];

    // K: streamed once -> non-temporal
    const vf4 q4 = *reinterpret_cast<const vf4*>(q + 4 * lane);
    const float* Kp = K + (size_t)(r0 + wave * 8) * D_DIM + 4 * lane;
    vf4 kv[8];
    #pragma unroll
    for (int k = 0; k < 8; ++k)
        kv[k] = __builtin_nontemporal_load(
                    reinterpret_cast<const vf4*>(Kp + (size_t)k * D_DIM));

    #pragma unroll
    for (int k = 0; k < 8; ++k) {
        float d = kv[k].x * q4.x + kv[k].y * q4.y + kv[k].z * q4.z + kv[k].w * q4.w;
        #pragma unroll
        for (int off = 32; off > 0; off >>= 1) d += __shfl_xor(d, off, 64);
        if (lane == 0) s_lds[wave * 8 + k] = d;
    }
    __syncthreads();   // only barrier

    if (t < C_ROWS) s_g[r0 + t] = s_lds[t];

    float m_c = -INFINITY;
    #pragma unroll
    for (int j = 0; j < C_ROWS; ++j) m_c = fmaxf(m_c, s_lds[j]);

    float u_c = 0.f, w = 0.f;
    #pragma unroll
    for (int j = 0; j < C_ROWS; ++j) {
        const float cf = __expf(s_lds[j] - m_c);
        u_c += cf;
        w = fmaf(cf, v[j], w);
    }

    cw[(size_t)c * D_DIM + t] = w;
    if (t == 0) { cm[c] = m_c; cu[c] = u_c; }
}

// ---------------- kCB: redundant scalar scan + per-super vector scan -------
// 64 blocks. Each block computes the FULL 2048-chunk (m,u) scan in LDS
// (16 KB of LLC-hot data, ~2us), block 0 publishes pm/pu, then each block
// does its super's within-super vector scan (pwl, T) and writes gsup[S].
__global__ __launch_bounds__(256) void kCB_scan(
    const float* __restrict__ cm, const float* __restrict__ cu,
    const float* __restrict__ cw,
    float* __restrict__ pm, float* __restrict__ pu,
    float* __restrict__ gsup,
    float* __restrict__ pwl, float* __restrict__ T)
{
    const int t = threadIdx.x;
    const int S = blockIdx.x;
    __shared__ float Lm[256], Lu[256];
    __shared__ float pmL[N_CHUNK + 1];
    __shared__ float ca[SUPER], cb[SUPER];

    // per-thread aggregate of 8 chunks
    float am[8], au[8];
    float M = -INFINITY, U = 0.f;
    #pragma unroll
    for (int j = 0; j < 8; ++j) {
        am[j] = cm[8 * t + j]; au[j] = cu[8 * t + j];
        const float mm = fmaxf(M, am[j]);
        U = U * __expf(M - mm) + au[j] * __expf(am[j] - mm);
        M = mm;
    }
    Lm[t] = M; Lu[t] = U;
    float Mi = M, Ui = U;
    __syncthreads();
    for (int off = 1; off < 256; off <<= 1) {
        float m1 = 0.f, u1 = 0.f;
        const bool act = (t >= off);
        if (act) { m1 = Lm[t - off]; u1 = Lu[t - off]; }
        __syncthreads();
        if (act) {
            const float mm = fmaxf(m1, Mi);
            Ui = u1 * __expf(m1 - mm) + Ui * __expf(Mi - mm);
            Mi = mm;
            Lm[t] = Mi; Lu[t] = Ui;
        }
        __syncthreads();
    }
    float Me = (t == 0) ? -INFINITY : Lm[t - 1];
    float Ue = (t == 0) ? 0.f : Lu[t - 1];
    #pragma unroll
    for (int j = 0; j < 8; ++j) {
        pmL[8 * t + j] = Me;
        if (S == 0) { pm[8 * t + j] = Me; pu[8 * t + j] = Ue; }
        const float mm = fmaxf(Me, am[j]);
        Ue = Ue * __expf(Me - mm) + au[j] * __expf(am[j] - mm);
        Me = mm;
    }
    if (t == 255) {
        pmL[N_CHUNK] = Me;
        if (S == 0) { pm[N_CHUNK] = Me; pu[N_CHUNK] = Ue; }
    }
    __syncthreads();

    // prefetch this super's cw (independent loads)
    float wv[SUPER];
    const float* cwp = cw + (size_t)S * SUPER * D_DIM + t;
    #pragma unroll
    for (int j = 0; j < SUPER; ++j) wv[j] = cwp[(size_t)j * D_DIM];

    if (t < SUPER) {
        const int c = S * SUPER + t;
        ca[t] = __expf(pmL[c] - pmL[c + 1]);   // c=0: exp(-inf)=0
        cb[t] = __expf(cm[c] - pmL[c + 1]);
    }
    if (t == 0)
        gsup[S] = __expf(pmL[S * SUPER] - pmL[S * SUPER + SUPER]); // S=0: 0
    __syncthreads();

    float PW = 0.f;
    float* pwlp = pwl + (size_t)S * SUPER * D_DIM + t;
    #pragma unroll
    for (int j = 0; j < SUPER; ++j) {
        pwlp[(size_t)j * D_DIM] = PW;
        PW = PW * ca[j] + wv[j] * cb[j];
    }
    T[(size_t)S * D_DIM + t] = PW;
}

// ---------------- kF: inline cross-super seed + local scan + output --------
__global__ __launch_bounds__(256) void kF_output(
    const float* __restrict__ V, const float* __restrict__ s_g,
    const float* __restrict__ pm, const float* __restrict__ pu,
    const float* __restrict__ pwl, const float* __restrict__ T,
    const float* __restrict__ gsup,
    float* __restrict__ out)
{
    const int t = threadIdx.x;
    const int c = blockIdx.x;
    const int S = c / SUPER;
    const int r0 = c * C_ROWS;
    const int wave = t >> 6, lane = t & 63;

    __shared__ float sa[C_ROWS], se[C_ROWS], sri[C_ROWS];
    __shared__ float gl[N_SUPER];

    // V loads first: 32 independent coalesced loads
    float v[C_ROWS];
    const float* Vp = V + (size_t)r0 * D_DIM + t;
    #pragma unroll
    for (int j = 0; j < C_ROWS; ++j) v[j] = Vp[(size_t)j * D_DIM];

    const float seed_pwl = pwl[(size_t)c * D_DIM + t];
    const float pmc = pm[c];
    const float pmS = pm[S * SUPER];

    if (t < N_SUPER) gl[t] = gsup[t];

    // wave 0: barrier-free shuffle scan over the 32 rows
    if (wave == 0) {
        const float puc = pu[c];
        float s_val = -INFINITY;
        if (lane < C_ROWS) s_val = s_g[r0 + lane];
        float m = s_val, u = 1.0f;
        #pragma unroll
        for (int off = 1; off < C_ROWS; off <<= 1) {
            const float m1 = __shfl_up(m, off, 32);
            const float u1 = __shfl_up(u, off, 32);
            if ((lane & 31) >= off) {
                const float mm = fmaxf(m1, m);
                u = u1 * __expf(m1 - mm) + u * __expf(m - mm);
                m = mm;
            }
        }
        const float m_row = fmaxf(pmc, m);
        const float u_row = puc * __expf(pmc - m_row) + u * __expf(m - m_row);
        const float m_prev_raw = __shfl_up(m_row, 1, 32);
        const float m_prev = ((lane & 31) == 0) ? pmc : m_prev_raw;
        if (lane < C_ROWS) {
            sa[lane]  = __expf(m_prev - m_row);   // row0 of chunk0: exp(-inf)=0
            se[lane]  = __expf(s_val - m_row);
            sri[lane] = 1.0f / u_row;
        }
    }
    __syncthreads();   // only barrier

    // inline kD: SW = exclusive cross-super vector prefix, frame pm[32S]
    float SW = 0.f;
    const float* Tp = T + t;
    #pragma unroll 8
    for (int Sp = 0; Sp < S; ++Sp)
        SW = SW * gl[Sp] + Tp[(size_t)Sp * D_DIM];

    const float gf = (c == 0) ? 0.f : __expf(pmS - pmc);
    float W = SW * gf + seed_pwl;

    float* Op = out + (size_t)r0 * D_DIM + t;
    #pragma unroll
    for (int j = 0; j < C_ROWS; ++j) {
        W = W * sa[j] + v[j] * se[j];
        __builtin_nontemporal_store(W * sri[j], Op + (size_t)j * D_DIM);
    }
}

extern "C" void kernel_launch(void* const* d_in, const int* in_sizes, int n_in,
                              void* d_out, int out_size, void* d_ws, size_t ws_size,
                              hipStream_t stream) {
    const float* K = (const float*)d_in[0];
    const float* V = (const float*)d_in[1];
    const float* q = (const float*)d_in[2];
    float* out = (float*)d_out;

    float* ws   = (float*)d_ws;
    float* s_g  = ws;                                  // 65536
    float* cm   = s_g + L_TOTAL;                       // 2048
    float* cu   = cm + N_CHUNK;                        // 2048
    float* pm   = cu + N_CHUNK;                        // 2049 (+pad)
    float* pu   = pm + (N_CHUNK + 16);                 // 2049 (+pad)
    float* gsup = pu + (N_CHUNK + 16);                 // 64 (+pad)
    float* cw   = gsup + 128;                          // 2048*256
    float* pwl  = cw + (size_t)N_CHUNK * D_DIM;        // 2048*256
    float* T    = pwl + (size_t)N_CHUNK * D_DIM;       // 64*256

    kA_aggregate<<<N_CHUNK, 256, 0, stream>>>(K, V, q, s_g, cm, cu, cw);
    kCB_scan<<<N_SUPER, 256, 0, stream>>>(cm, cu, cw, pm, pu, gsup, pwl, T);
    kF_output<<<N_CHUNK, 256, 0, stream>>>(V, s_g, pm, pu, pwl, T, gsup, out);
}